// Round 10
// baseline (205.813 us; speedup 1.0000x reference)
//
#include <hip/hip_runtime.h>
#include <math.h>

#define BB 8
#define NN 2048
#define NPOINT 102
#define H_REP 0.0005f
#define NBLK_UKNN (20 * 8 * 5)

typedef float v2f __attribute__((ext_vector_type(2)));

__device__ const int    c_ns[5]   = {8, 12, 16, 20, 24};
__device__ const double c_p[5]    = {0.004, 0.006, 0.008, 0.01, 0.012};
__device__ const int    c_goff[5] = {0, 6528, 16320, 29376, 45696};  // ints; 816*ns prefix

// branchless sorted-5 insert (keeps t0<=t1<=t2<=t3<=t4)
__device__ inline void ins5(float c, float& t0, float& t1, float& t2, float& t3, float& t4) {
    float lo;
    lo = fminf(t0, c); c = fmaxf(t0, c); t0 = lo;
    lo = fminf(t1, c); c = fmaxf(t1, c); t1 = lo;
    lo = fminf(t2, c); c = fmaxf(t2, c); t2 = lo;
    lo = fminf(t3, c); c = fmaxf(t3, c); t3 = lo;
    t4 = fminf(t4, c);
}

// ---------------- FPS: 1 wave/batch; coords in LDS (read each step), ONLY dist[32]
// in registers -> ~110 peak VGPR, no scratch (r6/r9 failure mode avoided). ----------
__global__ __launch_bounds__(64, 1) void k_fps(const float* __restrict__ pred,
                                               int* __restrict__ fidx) {
    int b = blockIdx.x;
    int lane = threadIdx.x;
    __shared__ float4 sP[NN];  // 32 KB, written once
    const float* pp = pred + (size_t)b * NN * 3;
    float dist[32];
#pragma unroll
    for (int k = 0; k < 32; k++) {
        int i = (k << 6) | lane;
        sP[i] = make_float4(pp[i * 3 + 0], pp[i * 3 + 1], pp[i * 3 + 2], 0.f);
        dist[k] = 1e10f;
    }
    if (lane == 0) fidx[b * NPOINT + 0] = 0;
    float lx = pp[0], ly = pp[1], lz = pp[2];
#pragma unroll 1
    for (int step = 1; step < NPOINT; ++step) {
        // update dists: 32 ds_read_b128 (base + k*1024 imm offsets), independent
#pragma unroll
        for (int k = 0; k < 32; k++) {
            float4 p = sP[(k << 6) | lane];  // single-wave: lgkmcnt orders vs our writes
            float dx = p.x - lx, dy = p.y - ly, dz = p.z - lz;
            dist[k] = fminf(dist[k], dx * dx + dy * dy + dz * dz);
        }
        // in-lane value max (tree, depth 6)
        float m[16];
#pragma unroll
        for (int k = 0; k < 16; k++) m[k] = fmaxf(dist[k], dist[k + 16]);
#pragma unroll
        for (int s = 8; s >= 1; s >>= 1) {
#pragma unroll
            for (int k = 0; k < s; k++) m[k] = fmaxf(m[k], m[k + s]);
        }
        float bv = m[0];
        // in-lane first-index of max: min global idx where dist[k]==bv (exact: bv is
        // an fmax of these very bits; matches jnp.argmax first-index semantics)
        int cand[16];
#pragma unroll
        for (int k = 0; k < 16; k++) {
            int cA = (dist[k] == bv) ? ((k << 6) | lane) : 0x7fffffff;
            int cB = (dist[k + 16] == bv) ? (((k + 16) << 6) | lane) : 0x7fffffff;
            cand[k] = min(cA, cB);
        }
#pragma unroll
        for (int s = 8; s >= 1; s >>= 1) {
#pragma unroll
            for (int k = 0; k < s; k++) cand[k] = min(cand[k], cand[k + s]);
        }
        int bi = cand[0];
        // wave-64 joint (value,idx) argmax via DPP; idempotent -> bcast-safe
        {
            float v2; int i2; bool take;
#define DPPC(CTRL)                                                                          \
            v2 = __int_as_float(__builtin_amdgcn_update_dpp(                                \
                    __float_as_int(bv), __float_as_int(bv), CTRL, 0xF, 0xF, false));        \
            i2 = __builtin_amdgcn_update_dpp(bi, bi, CTRL, 0xF, 0xF, false);                \
            take = (v2 > bv) || (v2 == bv && i2 < bi);                                      \
            bv = take ? v2 : bv; bi = take ? i2 : bi;
            DPPC(0x121)  // row_ror:1
            DPPC(0x122)  // row_ror:2
            DPPC(0x124)  // row_ror:4
            DPPC(0x128)  // row_ror:8
            DPPC(0x142)  // row_bcast15
            DPPC(0x143)  // row_bcast31
#undef DPPC
        }
        int fi = __builtin_amdgcn_readlane(bi, 63);  // SALU broadcast
        float4 lp = sP[fi];
        lx = lp.x; ly = lp.y; lz = lp.z;
        if (lane == 0) fidx[b * NPOINT + step] = fi;  // no barrier -> never drained
    }
}

union SMem {
    struct { float4 sB[NN]; float pm[4][128]; } cd;        // 32K + 2K
    struct { float4 sP[NN]; float pm[4][64][5]; } rep;     // 32K + 5K
};

// ---------------- cd+rep: blocks [0,256)=cd  [256,512)=rep ----------------
__global__ __launch_bounds__(256, 2) void k_cdrep(const float* __restrict__ pred,
                                                  const float* __restrict__ gt,
                                                  double* __restrict__ acc) {
    __shared__ SMem sm;
    int bid = blockIdx.x;
    int tid = threadIdx.x;
    int lane = tid & 63, wid = tid >> 6;

    if (bid < 256) {
        // ========== chamfer: 2 rows/lane (128 rows/block), 4 waves x 512-pt chunks ==========
        int r = bid;
        int z = r >> 7;
        int b = (r >> 4) & 7;
        int xb = r & 15;
        const float* A = z ? pred : gt;
        const float* Bp = z ? gt : pred;
        const float* bb = Bp + (size_t)b * NN * 3;
        for (int j = tid; j < NN; j += 256) {
            sm.cd.sB[j] = make_float4(bb[j * 3 + 0], bb[j * 3 + 1], bb[j * 3 + 2], 0.0f);
        }
        int rowA = xb * 128 + lane;
        int rowB = rowA + 64;
        const float* aA = A + ((size_t)b * NN + rowA) * 3;
        const float* aB = A + ((size_t)b * NN + rowB) * 3;
        float axA = aA[0], ayA = aA[1], azA = aA[2];
        float axB = aB[0], ayB = aB[1], azB = aB[2];
        __syncthreads();
        float mnA = 1e30f, mnB = 1e30f;
        int j0 = wid * 512;
#pragma unroll 8
        for (int jj = 0; jj < 512; jj++) {
            float4 p = sm.cd.sB[j0 + jj];
            float dxA = axA - p.x, dyA = ayA - p.y, dzA = azA - p.z;
            mnA = fminf(mnA, dxA * dxA + dyA * dyA + dzA * dzA);
            float dxB = axB - p.x, dyB = ayB - p.y, dzB = azB - p.z;
            mnB = fminf(mnB, dxB * dxB + dyB * dyB + dzB * dzB);
        }
        sm.cd.pm[wid][lane] = mnA;
        sm.cd.pm[wid][64 + lane] = mnB;
        __syncthreads();
        if (tid < 128) {
            double v = (double)fminf(fminf(sm.cd.pm[0][tid], sm.cd.pm[1][tid]),
                                     fminf(sm.cd.pm[2][tid], sm.cd.pm[3][tid]));
            for (int off = 32; off; off >>= 1) v += __shfl_down(v, off, 64);
            if (lane == 0) atomicAdd(acc + z, v);
        }
    } else {
        // ========== repulsion: 4 waves x 512-pt chunks, 64 rows/block ==========
        int r = bid - 256;
        int b = r >> 5;
        int xb = r & 31;
        const float* pp = pred + (size_t)b * NN * 3;
        for (int j = tid; j < NN; j += 256) {
            sm.rep.sP[j] = make_float4(pp[j * 3 + 0], pp[j * 3 + 1], pp[j * 3 + 2], 0.0f);
        }
        int row = xb * 64 + lane;
        __syncthreads();
        float4 q = sm.rep.sP[row];
        float t0 = 1e30f, t1 = 1e30f, t2 = 1e30f, t3 = 1e30f, t4 = 1e30f;
        int j0 = wid * 512;
#pragma unroll 8
        for (int jj = 0; jj < 512; jj++) {
            float4 p = sm.rep.sP[j0 + jj];
            float dx = q.x - p.x, dy = q.y - p.y, dz = q.z - p.z;
            ins5(dx * dx + dy * dy + dz * dz, t0, t1, t2, t3, t4);
        }
        sm.rep.pm[wid][lane][0] = t0; sm.rep.pm[wid][lane][1] = t1;
        sm.rep.pm[wid][lane][2] = t2; sm.rep.pm[wid][lane][3] = t3;
        sm.rep.pm[wid][lane][4] = t4;
        __syncthreads();
        double v = 0.0;
        if (tid < 64) {
            t0 = sm.rep.pm[0][lane][0]; t1 = sm.rep.pm[0][lane][1]; t2 = sm.rep.pm[0][lane][2];
            t3 = sm.rep.pm[0][lane][3]; t4 = sm.rep.pm[0][lane][4];
#pragma unroll
            for (int w = 1; w < 4; w++) {
#pragma unroll
                for (int k = 0; k < 5; k++) ins5(sm.rep.pm[w][lane][k], t0, t1, t2, t3, t4);
            }
            float s = fmaxf(H_REP - t1, 0.f) + fmaxf(H_REP - t2, 0.f) +
                      fmaxf(H_REP - t3, 0.f) + fmaxf(H_REP - t4, 0.f);
            v = (double)s;
            for (int off = 32; off; off >>= 1) v += __shfl_down(v, off, 64);
            if (tid == 0) atomicAdd(acc + 2, v);
        }
    }
}

// ---------------- ball query, all 5 radii fused; 4 centers/block, no LDS ----------------
__global__ __launch_bounds__(256) void k_ball(const float* __restrict__ pcd,
                                              const int* __restrict__ fidx,
                                              int* __restrict__ gidx) {
    int pi = blockIdx.z;
    int b = blockIdx.y;
    int wid = threadIdx.x >> 6, lane = threadIdx.x & 63;
    int c = blockIdx.x * 4 + wid;
    if (c >= NPOINT) return;
    int ns = c_ns[pi];
    double rd = sqrt(c_p[pi]);
    float r2 = (float)(rd * rd);
    const float* pp = pcd + (size_t)b * NN * 3;
    int ci = fidx[b * NPOINT + c];
    float cx = pp[ci * 3 + 0], cy = pp[ci * 3 + 1], cz = pp[ci * 3 + 2];
    float sc = cx * cx + cy * cy + cz * cz;
    int* out = gidx + c_goff[pi] + ((size_t)b * NPOINT + c) * ns;
    int cnt = 0;
    int first = 0;
    for (int j0 = 0; j0 < NN && cnt < ns; j0 += 64) {
        int j = j0 + lane;
        float x = pp[j * 3 + 0], y = pp[j * 3 + 1], z = pp[j * 3 + 2];
        float sj = x * x + y * y + z * z;
        float d2 = fmaxf(sc + sj - 2.0f * (cx * x + cy * y + cz * z), 0.0f);
        bool pred2 = d2 < r2;
        unsigned long long mask = __ballot(pred2);
        if (cnt == 0 && mask != 0ull) first = j0 + (int)__builtin_ctzll(mask);
        if (pred2) {
            int pos = cnt + (int)__popcll(mask & ((1ull << lane) - 1ull));
            if (pos < ns) out[pos] = j;
        }
        cnt += (int)__popcll(mask);
    }
    if (cnt < ns) {
        for (int s = cnt + lane; s < ns; s += 64) out[s] = first;
    }
}

// ---------------- kNN-2, all 5 fused: packed-f32, 2 rows/lane; last block runs final ----
__global__ __launch_bounds__(256) void k_uknn(const float* __restrict__ pcd,
                                              const int* __restrict__ gidx,
                                              double* __restrict__ acc,
                                              int* __restrict__ done,
                                              const float* __restrict__ radius,
                                              float* __restrict__ out) {
    __shared__ v2f sX[1224], sY[1224], sZ[1224];  // SoA pairs, ~29.4 KB
    __shared__ float pm1[4][128], pm2[4][128];    // 4 KB
    __shared__ int lastFlag;
    int pi = blockIdx.z;
    int b = blockIdx.y;
    int ns = c_ns[pi];
    int M = NPOINT * ns;  // 816..2448, divisible by 8
    bool active = (blockIdx.x * 128 < M);
    if (active) {
        const float* pp = pcd + (size_t)b * NN * 3;
        const int* gb = gidx + c_goff[pi] + (size_t)b * NPOINT * ns;
        float* fX = (float*)sX; float* fY = (float*)sY; float* fZ = (float*)sZ;
        for (int g = threadIdx.x; g < M; g += 256) {
            int id = gb[g];
            fX[g] = pp[id * 3 + 0]; fY[g] = pp[id * 3 + 1]; fZ[g] = pp[id * 3 + 2];
        }
        int lane = threadIdx.x & 63, wid = threadIdx.x >> 6;
        int rowA = blockIdx.x * 128 + lane;
        int rowB = rowA + 64;
        __syncthreads();
        float qAx = 0.f, qAy = 0.f, qAz = 0.f, qBx = 0.f, qBy = 0.f, qBz = 0.f;
        if (rowA < M) { qAx = fX[rowA]; qAy = fY[rowA]; qAz = fZ[rowA]; }
        if (rowB < M) { qBx = fX[rowB]; qBy = fY[rowB]; qBz = fZ[rowB]; }
        v2f qax = {qAx, qAx}, qay = {qAy, qAy}, qaz = {qAz, qAz};
        v2f qbx = {qBx, qBx}, qby = {qBy, qBy}, qbz = {qBz, qBz};
        v2f m1A = {1e30f, 1e30f}, m2A = {1e30f, 1e30f};
        v2f m1B = {1e30f, 1e30f}, m2B = {1e30f, 1e30f};
        int Mh = M >> 3;  // v2f pairs per wave chunk
        int j0 = wid * Mh;
#pragma unroll 4
        for (int jj = 0; jj < Mh; jj++) {
            v2f X = sX[j0 + jj], Y = sY[j0 + jj], Z = sZ[j0 + jj];
            // direct formula: exact 0 for bit-identical duplicates (padding!)
            v2f dxA = qax - X, dyA = qay - Y, dzA = qaz - Z;
            v2f dA = dxA * dxA + dyA * dyA + dzA * dzA;  // v_pk_mul/fma_f32
            float l0 = fminf(m1A.x, dA.x), h0 = fmaxf(m1A.x, dA.x);
            float l1 = fminf(m1A.y, dA.y), h1 = fmaxf(m1A.y, dA.y);
            m1A = (v2f){l0, l1};
            m2A = (v2f){fminf(m2A.x, h0), fminf(m2A.y, h1)};
            v2f dxB = qbx - X, dyB = qby - Y, dzB = qbz - Z;
            v2f dB = dxB * dxB + dyB * dyB + dzB * dzB;
            float l2 = fminf(m1B.x, dB.x), h2 = fmaxf(m1B.x, dB.x);
            float l3 = fminf(m1B.y, dB.y), h3 = fmaxf(m1B.y, dB.y);
            m1B = (v2f){l2, l3};
            m2B = (v2f){fminf(m2B.x, h2), fminf(m2B.y, h3)};
        }
        // merge even/odd streams (exact: multiset (min1,min2) is order-independent)
        float a1 = fminf(m1A.x, m1A.y);
        float a2 = fminf(fmaxf(m1A.x, m1A.y), fminf(m2A.x, m2A.y));
        float b1 = fminf(m1B.x, m1B.y);
        float b2 = fminf(fmaxf(m1B.x, m1B.y), fminf(m2B.x, m2B.y));
        pm1[wid][lane] = a1; pm2[wid][lane] = a2;
        pm1[wid][64 + lane] = b1; pm2[wid][64 + lane] = b2;
        __syncthreads();
        if (threadIdx.x < 128) {
            int row = blockIdx.x * 128 + threadIdx.x;
            double v = 0.0;
            if (row < M) {
                float c1 = pm1[0][threadIdx.x], c2 = pm2[0][threadIdx.x];
#pragma unroll
                for (int w = 1; w < 4; w++) {
                    float d1 = pm1[w][threadIdx.x], d2 = pm2[w][threadIdx.x];
                    float n1 = fminf(c1, d1);
                    float n2 = fminf(fmaxf(c1, d1), fminf(c2, d2));
                    c1 = n1; c2 = n2;
                }
                v = (double)(sqrtf(c2) + 1e-8f);
            }
            for (int off = 32; off; off >>= 1) v += __shfl_down(v, off, 64);
            if ((threadIdx.x & 63) == 0) atomicAdd(acc + 3 + pi * 8 + b, v);
        }
    }
    // -------- last-block-done: fused finalize --------
    __threadfence();
    __syncthreads();
    if (threadIdx.x == 0) lastFlag = (atomicAdd(done, 1) == NBLK_UKNN - 1);
    __syncthreads();
    if (!lastFlag) return;
    __threadfence();
    int lane = threadIdx.x;
    if (lane >= 64) return;
    double v = 0.0;
    if (lane < 40) {
        int pi2 = lane >> 3;
        int b2 = lane & 7;
        double p = c_p[pi2];
        int M2 = NPOINT * c_ns[pi2];
        double disk_area = M_PI * 1.0 / (double)NN;
        double e = sqrt(disk_area);
        double m = __hip_atomic_load(&acc[3 + pi2 * 8 + b2], __ATOMIC_RELAXED,
                                     __HIP_MEMORY_SCOPE_AGENT) / (double)M2;
        double d = m - e;
        double w = (p * 100.0) * (p * 100.0);
        v = d * d / (e + 1e-8) * w / 40.0;  // /(8 batches * 5 percentages)
    }
    for (int off = 32; off; off >>= 1) v += __shfl_down(v, off, 64);
    if (lane == 0) {
        double a0 = __hip_atomic_load(&acc[0], __ATOMIC_RELAXED, __HIP_MEMORY_SCOPE_AGENT);
        double a1 = __hip_atomic_load(&acc[1], __ATOMIC_RELAXED, __HIP_MEMORY_SCOPE_AGENT);
        double a2 = __hip_atomic_load(&acc[2], __ATOMIC_RELAXED, __HIP_MEMORY_SCOPE_AGENT);
        double cd = (0.8 * a0 + 0.2 * a1) / ((double)BB * NN) / (double)radius[0];
        double rep = a2 / ((double)BB * NN * 4.0);
        out[0] = (float)(cd + rep + v);
    }
}

extern "C" void kernel_launch(void* const* d_in, const int* in_sizes, int n_in,
                              void* d_out, int out_size, void* d_ws, size_t ws_size,
                              hipStream_t stream) {
    const float* pred = (const float*)d_in[0];
    const float* gt = (const float*)d_in[1];
    const float* radius = (const float*)d_in[2];
    float* out = (float*)d_out;

    double* acc = (double*)d_ws;             // 48 doubles: 0=for 1=bac 2=rep 3..42=uni[5][8]
    int* done = (int*)(acc + 48);            // uknn completion counter
    int* fidx = (int*)(acc + 50);            // 8*102 ints
    int* gidx = fidx + BB * NPOINT;          // 65280 ints (all 5 pi regions)

    hipMemsetAsync(d_ws, 0, 50 * sizeof(double), stream);  // zero acc + done
    hipLaunchKernelGGL(k_fps, dim3(BB), dim3(64), 0, stream, pred, fidx);
    hipLaunchKernelGGL(k_cdrep, dim3(512), dim3(256), 0, stream, pred, gt, acc);
    hipLaunchKernelGGL(k_ball, dim3(26, BB, 5), dim3(256), 0, stream, pred, fidx, gidx);
    hipLaunchKernelGGL(k_uknn, dim3(20, BB, 5), dim3(256), 0, stream, pred, gidx, acc,
                       done, radius, out);
}

// Round 11
// 149.889 us; speedup vs baseline: 1.3731x; 1.3731x over previous
//
#include <hip/hip_runtime.h>
#include <math.h>

#define BB 8
#define NN 2048
#define NPOINT 102
#define H_REP 0.0005f
#define NBLK_UKNN (20 * 8 * 5)

typedef float v2f __attribute__((ext_vector_type(2)));

__device__ const int    c_ns[5]   = {8, 12, 16, 20, 24};
__device__ const double c_p[5]    = {0.004, 0.006, 0.008, 0.01, 0.012};
__device__ const int    c_goff[5] = {0, 6528, 16320, 29376, 45696};  // ints; 816*ns prefix

// workspace layout (doubles): cdpart[512] | reppart[256] | ukpart[1600]
#define OFF_CD 0
#define OFF_REP 512
#define OFF_UK 768
#define N_DBL 2368

// branchless sorted-5 insert (keeps t0<=t1<=t2<=t3<=t4)
__device__ inline void ins5(float c, float& t0, float& t1, float& t2, float& t3, float& t4) {
    float lo;
    lo = fminf(t0, c); c = fmaxf(t0, c); t0 = lo;
    lo = fminf(t1, c); c = fmaxf(t1, c); t1 = lo;
    lo = fminf(t2, c); c = fmaxf(t2, c); t2 = lo;
    lo = fminf(t3, c); c = fmaxf(t3, c); t3 = lo;
    t4 = fminf(t4, c);
}

union SMem {
    struct { float4 sB[NN]; float pm[4][128]; double ps[2]; } cd;   // 32K + 2K
    struct { float4 sP[NN]; float pm[4][64][5]; } rep;              // 32K + 5K
    struct { float4 sP[NN]; float2 sl[2][4]; } fps;                 // 32K + 64B
};

// ---------------- phase1: blocks [0,8)=fps  [8,264)=cd  [264,520)=rep ----------------
// (r7 structure verbatim: measured 91 us with fps hidden under cd/rep)
__global__ __launch_bounds__(256, 2) void k_phase1(const float* __restrict__ pred,
                                                   const float* __restrict__ gt,
                                                   int* __restrict__ fidx,
                                                   double* __restrict__ part,
                                                   int* __restrict__ done) {
    __shared__ SMem sm;
    int bid = blockIdx.x;
    int tid = threadIdx.x;
    int lane = tid & 63, wid = tid >> 6;

    if (bid == 8 && tid == 0) *done = 0;  // zero the uknn completion counter (no memset)

    if (bid < 8) {
        // ========== FPS: 4 waves x 8 pts/lane, DPP argmax, 1-barrier slot merge ==========
        __builtin_amdgcn_s_setprio(1);
        int b = bid;
        const float* pp = pred + (size_t)b * NN * 3;
        float px[8], py[8], pz[8], dist[8];
#pragma unroll
        for (int k = 0; k < 8; k++) {
            int i = (wid << 9) + (k << 6) + lane;  // wave wid owns [wid*512, wid*512+512)
            float x = pp[i * 3 + 0], y = pp[i * 3 + 1], z = pp[i * 3 + 2];
            px[k] = x; py[k] = y; pz[k] = z; dist[k] = 1e10f;
            sm.fps.sP[i] = make_float4(x, y, z, 0.0f);
        }
        if (tid == 0) fidx[b * NPOINT + 0] = 0;
        __syncthreads();
        int last = 0;
#pragma unroll 1
        for (int step = 1; step < NPOINT; ++step) {
            float4 lp = sm.fps.sP[last];
            float bv = -1.0f;
            int bi = 0;
#pragma unroll
            for (int k = 0; k < 8; k++) {
                float dx = px[k] - lp.x, dy = py[k] - lp.y, dz = pz[k] - lp.z;
                float nd = fminf(dist[k], dx * dx + dy * dy + dz * dz);
                dist[k] = nd;
                bool better = nd > bv;  // ascending k -> first-max kept (min global idx)
                bv = better ? nd : bv;
                bi = better ? ((wid << 9) + (k << 6) + lane) : bi;
            }
            // wave-64 argmax in-register: row_ror 1,2,4,8 then bcast15, bcast31.
            // pcomb is idempotent (max, tie->min idx) so bcast double-combines are safe.
            {
                float v2; int i2; bool take;
#define DPPC(CTRL)                                                                          \
                v2 = __int_as_float(__builtin_amdgcn_update_dpp(                            \
                        __float_as_int(bv), __float_as_int(bv), CTRL, 0xF, 0xF, false));    \
                i2 = __builtin_amdgcn_update_dpp(bi, bi, CTRL, 0xF, 0xF, false);            \
                take = (v2 > bv) || (v2 == bv && i2 < bi);                                  \
                bv = take ? v2 : bv; bi = take ? i2 : bi;
                DPPC(0x121)  // row_ror:1
                DPPC(0x122)  // row_ror:2
                DPPC(0x124)  // row_ror:4
                DPPC(0x128)  // row_ror:8
                DPPC(0x142)  // row_bcast15
                DPPC(0x143)  // row_bcast31
#undef DPPC
            }
            int pb = step & 1;
            if (lane == 63) sm.fps.sl[pb][wid] = make_float2(bv, __int_as_float(bi));
            __syncthreads();
            // all threads redundantly merge the 4 wave winners (broadcast LDS reads)
            float fv = -2.0f;
            int fi = 0;
#pragma unroll
            for (int w = 0; w < 4; w++) {  // ascending wave -> disjoint ascending idx ranges
                float2 s = sm.fps.sl[pb][w];
                int i2 = __float_as_int(s.y);
                bool take = (s.x > fv) || (s.x == fv && i2 < fi);
                fv = take ? s.x : fv;
                fi = take ? i2 : fi;
            }
            if (tid == 0) fidx[b * NPOINT + step] = fi;
            last = fi;  // uniform across block; no second barrier (double-buffered slots)
        }
    } else if (bid < 264) {
        // ========== chamfer: 2 rows/lane (128 rows/block), 4 waves x 512-pt chunks ==========
        int r = bid - 8;
        int z = r >> 7;
        int b = (r >> 4) & 7;
        int xb = r & 15;
        const float* A = z ? pred : gt;
        const float* Bp = z ? gt : pred;
        const float* bb = Bp + (size_t)b * NN * 3;
        for (int j = tid; j < NN; j += 256) {
            sm.cd.sB[j] = make_float4(bb[j * 3 + 0], bb[j * 3 + 1], bb[j * 3 + 2], 0.0f);
        }
        int rowA = xb * 128 + lane;
        int rowB = rowA + 64;
        const float* aA = A + ((size_t)b * NN + rowA) * 3;
        const float* aB = A + ((size_t)b * NN + rowB) * 3;
        float axA = aA[0], ayA = aA[1], azA = aA[2];
        float axB = aB[0], ayB = aB[1], azB = aB[2];
        __syncthreads();
        float mnA = 1e30f, mnB = 1e30f;
        int j0 = wid * 512;
#pragma unroll 8
        for (int jj = 0; jj < 512; jj++) {
            float4 p = sm.cd.sB[j0 + jj];
            float dxA = axA - p.x, dyA = ayA - p.y, dzA = azA - p.z;
            mnA = fminf(mnA, dxA * dxA + dyA * dyA + dzA * dzA);
            float dxB = axB - p.x, dyB = ayB - p.y, dzB = azB - p.z;
            mnB = fminf(mnB, dxB * dxB + dyB * dyB + dzB * dzB);
        }
        sm.cd.pm[wid][lane] = mnA;
        sm.cd.pm[wid][64 + lane] = mnB;
        __syncthreads();
        if (tid < 128) {
            double v = (double)fminf(fminf(sm.cd.pm[0][tid], sm.cd.pm[1][tid]),
                                     fminf(sm.cd.pm[2][tid], sm.cd.pm[3][tid]));
            for (int off = 32; off; off >>= 1) v += __shfl_down(v, off, 64);
            if (lane == 0) part[OFF_CD + r * 2 + (tid >> 6)] = v;  // two slots/block, no sync
        }
    } else {
        // ========== repulsion: 4 waves x 512-pt chunks, 64 rows/block ==========
        int r = bid - 264;
        int b = r >> 5;
        int xb = r & 31;
        const float* pp = pred + (size_t)b * NN * 3;
        for (int j = tid; j < NN; j += 256) {
            sm.rep.sP[j] = make_float4(pp[j * 3 + 0], pp[j * 3 + 1], pp[j * 3 + 2], 0.0f);
        }
        int row = xb * 64 + lane;
        __syncthreads();
        float4 q = sm.rep.sP[row];
        float t0 = 1e30f, t1 = 1e30f, t2 = 1e30f, t3 = 1e30f, t4 = 1e30f;
        int j0 = wid * 512;
#pragma unroll 8
        for (int jj = 0; jj < 512; jj++) {
            float4 p = sm.rep.sP[j0 + jj];
            float dx = q.x - p.x, dy = q.y - p.y, dz = q.z - p.z;
            ins5(dx * dx + dy * dy + dz * dz, t0, t1, t2, t3, t4);
        }
        sm.rep.pm[wid][lane][0] = t0; sm.rep.pm[wid][lane][1] = t1;
        sm.rep.pm[wid][lane][2] = t2; sm.rep.pm[wid][lane][3] = t3;
        sm.rep.pm[wid][lane][4] = t4;
        __syncthreads();
        if (tid < 64) {
            t0 = sm.rep.pm[0][lane][0]; t1 = sm.rep.pm[0][lane][1]; t2 = sm.rep.pm[0][lane][2];
            t3 = sm.rep.pm[0][lane][3]; t4 = sm.rep.pm[0][lane][4];
#pragma unroll
            for (int w = 1; w < 4; w++) {
#pragma unroll
                for (int k = 0; k < 5; k++) ins5(sm.rep.pm[w][lane][k], t0, t1, t2, t3, t4);
            }
            float s = fmaxf(H_REP - t1, 0.f) + fmaxf(H_REP - t2, 0.f) +
                      fmaxf(H_REP - t3, 0.f) + fmaxf(H_REP - t4, 0.f);
            double v = (double)s;
            for (int off = 32; off; off >>= 1) v += __shfl_down(v, off, 64);
            if (tid == 0) part[OFF_REP + r] = v;
        }
    }
}

// ---------------- ball query, all 5 radii fused; 4 centers/block, no LDS ----------------
__global__ __launch_bounds__(256) void k_ball(const float* __restrict__ pcd,
                                              const int* __restrict__ fidx,
                                              int* __restrict__ gidx) {
    int pi = blockIdx.z;
    int b = blockIdx.y;
    int wid = threadIdx.x >> 6, lane = threadIdx.x & 63;
    int c = blockIdx.x * 4 + wid;
    if (c >= NPOINT) return;
    int ns = c_ns[pi];
    double rd = sqrt(c_p[pi]);
    float r2 = (float)(rd * rd);
    const float* pp = pcd + (size_t)b * NN * 3;
    int ci = fidx[b * NPOINT + c];
    float cx = pp[ci * 3 + 0], cy = pp[ci * 3 + 1], cz = pp[ci * 3 + 2];
    float sc = cx * cx + cy * cy + cz * cz;
    int* out = gidx + c_goff[pi] + ((size_t)b * NPOINT + c) * ns;
    int cnt = 0;
    int first = 0;
    for (int j0 = 0; j0 < NN && cnt < ns; j0 += 64) {
        int j = j0 + lane;
        float x = pp[j * 3 + 0], y = pp[j * 3 + 1], z = pp[j * 3 + 2];
        float sj = x * x + y * y + z * z;
        float d2 = fmaxf(sc + sj - 2.0f * (cx * x + cy * y + cz * z), 0.0f);
        bool pred2 = d2 < r2;
        unsigned long long mask = __ballot(pred2);
        if (cnt == 0 && mask != 0ull) first = j0 + (int)__builtin_ctzll(mask);
        if (pred2) {
            int pos = cnt + (int)__popcll(mask & ((1ull << lane) - 1ull));
            if (pos < ns) out[pos] = j;
        }
        cnt += (int)__popcll(mask);
    }
    if (cnt < ns) {
        for (int s = cnt + lane; s < ns; s += 64) out[s] = first;
    }
}

// ---------------- kNN-2, all 5 fused: packed-f32, 2 rows/lane; last block finalizes ----
__global__ __launch_bounds__(256) void k_uknn(const float* __restrict__ pcd,
                                              const int* __restrict__ gidx,
                                              double* __restrict__ part,
                                              int* __restrict__ done,
                                              const float* __restrict__ radius,
                                              float* __restrict__ out) {
    __shared__ v2f sX[1224], sY[1224], sZ[1224];  // SoA pairs, ~29.4 KB
    __shared__ float pm1[4][128], pm2[4][128];    // 4 KB
    __shared__ int lastFlag;
    int pi = blockIdx.z;
    int b = blockIdx.y;
    int ns = c_ns[pi];
    int M = NPOINT * ns;  // 816..2448, divisible by 8
    int slot = OFF_UK + (((pi * 8 + b) * 20) + blockIdx.x) * 2;
    bool active = (blockIdx.x * 128 < M);
    if (active) {
        const float* pp = pcd + (size_t)b * NN * 3;
        const int* gb = gidx + c_goff[pi] + (size_t)b * NPOINT * ns;
        float* fX = (float*)sX; float* fY = (float*)sY; float* fZ = (float*)sZ;
        for (int g = threadIdx.x; g < M; g += 256) {
            int id = gb[g];
            fX[g] = pp[id * 3 + 0]; fY[g] = pp[id * 3 + 1]; fZ[g] = pp[id * 3 + 2];
        }
        int lane = threadIdx.x & 63, wid = threadIdx.x >> 6;
        int rowA = blockIdx.x * 128 + lane;
        int rowB = rowA + 64;
        __syncthreads();
        float qAx = 0.f, qAy = 0.f, qAz = 0.f, qBx = 0.f, qBy = 0.f, qBz = 0.f;
        if (rowA < M) { qAx = fX[rowA]; qAy = fY[rowA]; qAz = fZ[rowA]; }
        if (rowB < M) { qBx = fX[rowB]; qBy = fY[rowB]; qBz = fZ[rowB]; }
        v2f qax = {qAx, qAx}, qay = {qAy, qAy}, qaz = {qAz, qAz};
        v2f qbx = {qBx, qBx}, qby = {qBy, qBy}, qbz = {qBz, qBz};
        v2f m1A = {1e30f, 1e30f}, m2A = {1e30f, 1e30f};
        v2f m1B = {1e30f, 1e30f}, m2B = {1e30f, 1e30f};
        int Mh = M >> 3;  // v2f pairs per wave chunk
        int j0 = wid * Mh;
#pragma unroll 4
        for (int jj = 0; jj < Mh; jj++) {
            v2f X = sX[j0 + jj], Y = sY[j0 + jj], Z = sZ[j0 + jj];
            // direct formula: exact 0 for bit-identical duplicates (padding!)
            v2f dxA = qax - X, dyA = qay - Y, dzA = qaz - Z;
            v2f dA = dxA * dxA + dyA * dyA + dzA * dzA;  // v_pk_mul/fma_f32
            float l0 = fminf(m1A.x, dA.x), h0 = fmaxf(m1A.x, dA.x);
            float l1 = fminf(m1A.y, dA.y), h1 = fmaxf(m1A.y, dA.y);
            m1A = (v2f){l0, l1};
            m2A = (v2f){fminf(m2A.x, h0), fminf(m2A.y, h1)};
            v2f dxB = qbx - X, dyB = qby - Y, dzB = qbz - Z;
            v2f dB = dxB * dxB + dyB * dyB + dzB * dzB;
            float l2 = fminf(m1B.x, dB.x), h2 = fmaxf(m1B.x, dB.x);
            float l3 = fminf(m1B.y, dB.y), h3 = fmaxf(m1B.y, dB.y);
            m1B = (v2f){l2, l3};
            m2B = (v2f){fminf(m2B.x, h2), fminf(m2B.y, h3)};
        }
        // merge even/odd streams (exact: multiset (min1,min2) is order-independent)
        float a1 = fminf(m1A.x, m1A.y);
        float a2 = fminf(fmaxf(m1A.x, m1A.y), fminf(m2A.x, m2A.y));
        float b1 = fminf(m1B.x, m1B.y);
        float b2 = fminf(fmaxf(m1B.x, m1B.y), fminf(m2B.x, m2B.y));
        pm1[wid][lane] = a1; pm2[wid][lane] = a2;
        pm1[wid][64 + lane] = b1; pm2[wid][64 + lane] = b2;
        __syncthreads();
        if (threadIdx.x < 128) {
            int row = blockIdx.x * 128 + threadIdx.x;
            double v = 0.0;
            if (row < M) {
                float c1 = pm1[0][threadIdx.x], c2 = pm2[0][threadIdx.x];
#pragma unroll
                for (int w = 1; w < 4; w++) {
                    float d1 = pm1[w][threadIdx.x], d2 = pm2[w][threadIdx.x];
                    float n1 = fminf(c1, d1);
                    float n2 = fminf(fmaxf(c1, d1), fminf(c2, d2));
                    c1 = n1; c2 = n2;
                }
                v = (double)(sqrtf(c2) + 1e-8f);
            }
            for (int off = 32; off; off >>= 1) v += __shfl_down(v, off, 64);
            if ((threadIdx.x & 63) == 0) part[slot + (threadIdx.x >> 6)] = v;
        }
    } else if (threadIdx.x == 0) {
        part[slot + 0] = 0.0;
        part[slot + 1] = 0.0;
    }
    // -------- last-block-done: fused finalize --------
    __threadfence();
    __syncthreads();
    if (threadIdx.x == 0) lastFlag = (atomicAdd(done, 1) == NBLK_UKNN - 1);
    __syncthreads();
    if (!lastFlag) return;
    __threadfence();
    int lane = threadIdx.x;
    if (lane >= 64) return;
    // cd partials: [0,256)=forward(z=0), [256,512)=backward; rep: 256; each lane takes 4
    double s0 = 0.0, s1 = 0.0, sr = 0.0;
#pragma unroll
    for (int k = 0; k < 4; k++) {
        s0 += __hip_atomic_load(&part[OFF_CD + lane + 64 * k], __ATOMIC_RELAXED,
                                __HIP_MEMORY_SCOPE_AGENT);
        s1 += __hip_atomic_load(&part[OFF_CD + 256 + lane + 64 * k], __ATOMIC_RELAXED,
                                __HIP_MEMORY_SCOPE_AGENT);
        sr += __hip_atomic_load(&part[OFF_REP + lane + 64 * k], __ATOMIC_RELAXED,
                                __HIP_MEMORY_SCOPE_AGENT);
    }
    // uniform-loss terms: lane<40 sums its (pi,b) group's 40 slots
    double v = 0.0;
    if (lane < 40) {
        int pi2 = lane >> 3;
        int b2 = lane & 7;
        double m = 0.0;
        int base = OFF_UK + (pi2 * 8 + b2) * 40;
        for (int k = 0; k < 40; k++) {
            m += __hip_atomic_load(&part[base + k], __ATOMIC_RELAXED,
                                   __HIP_MEMORY_SCOPE_AGENT);
        }
        double p = c_p[pi2];
        int M2 = NPOINT * c_ns[pi2];
        double disk_area = M_PI * 1.0 / (double)NN;
        double e = sqrt(disk_area);
        m = m / (double)M2;
        double d = m - e;
        double w = (p * 100.0) * (p * 100.0);
        v = d * d / (e + 1e-8) * w / 40.0;  // /(8 batches * 5 percentages)
    }
    for (int off = 32; off; off >>= 1) {
        v += __shfl_down(v, off, 64);
        s0 += __shfl_down(s0, off, 64);
        s1 += __shfl_down(s1, off, 64);
        sr += __shfl_down(sr, off, 64);
    }
    if (lane == 0) {
        double cd = (0.8 * s0 + 0.2 * s1) / ((double)BB * NN) / (double)radius[0];
        double rep = sr / ((double)BB * NN * 4.0);
        out[0] = (float)(cd + rep + v);
    }
}

extern "C" void kernel_launch(void* const* d_in, const int* in_sizes, int n_in,
                              void* d_out, int out_size, void* d_ws, size_t ws_size,
                              hipStream_t stream) {
    const float* pred = (const float*)d_in[0];
    const float* gt = (const float*)d_in[1];
    const float* radius = (const float*)d_in[2];
    float* out = (float*)d_out;

    double* part = (double*)d_ws;            // 2368 doubles of per-block partials
    int* done = (int*)(part + N_DBL);        // uknn completion counter (zeroed by phase1)
    int* fidx = (int*)(part + N_DBL + 1);    // 8*102 ints
    int* gidx = fidx + BB * NPOINT;          // 65280 ints (all 5 pi regions)

    hipLaunchKernelGGL(k_phase1, dim3(520), dim3(256), 0, stream, pred, gt, fidx, part, done);
    hipLaunchKernelGGL(k_ball, dim3(26, BB, 5), dim3(256), 0, stream, pred, fidx, gidx);
    hipLaunchKernelGGL(k_uknn, dim3(20, BB, 5), dim3(256), 0, stream, pred, gidx, part,
                       done, radius, out);
}